// Round 3
// baseline (6672.960 us; speedup 1.0000x reference)
//
#include <hip/hip_runtime.h>
#include <stdint.h>

// EncDecAD: encoder LSTM (256) -> Linear -> self-feeding decoder LSTM (256).
// Persistent: 256 blocks (1/CU), 16 groups x 16 blocks; group = 32 batch rows,
// block = 16 h-cols. Weights resident as MFMA B-frags in VGPRs.
// R6: K-SPLIT waves (replaces R5's LDS staging, which added an 8-way-conflicted
// LDS round trip on the critical path: 89M conflict cycles, +44% time).
//  - wave w loads ONLY k in [64w,64w+64) of the peer h-tile (4KB, no overlap;
//    was 4x16KB redundant) straight into registers, computes partials for ALL
//    four n-slices, then a small conflict-free LDS reduction (6 b128 writes +
//    barrier + 6 b128 reads + 24 adds) combines partials across waves.
//  - x-part MFMAs K-split identically (4x fewer cached loads + f2bf VALU).
//  - MFMA count unchanged; f32 reassociation only (<< 2e-3 tolerance).
//  - Keeps R5's bounded XCD-L2 fast-path gating (XCC-ID consensus + sc0
//    visibility self-test, agent-scope verdict exchange; polls bounded).
//    WRITE_SIZE is the engagement tell (drops ~134MB if sc0 stores stay in L2).

#define H_ 256
#define B_ 512
#define T_ 256

typedef short short8 __attribute__((ext_vector_type(8)));
typedef float f32x4 __attribute__((ext_vector_type(4)));
typedef uint32_t u32x4 __attribute__((ext_vector_type(4)));

__device__ __forceinline__ short f2bf(float f) {
  union { float f; uint32_t u; } v; v.f = f;
  uint32_t r = (v.u + 0x7FFFu + ((v.u >> 16) & 1u)) >> 16;  // RNE
  return (short)(uint16_t)r;
}

__device__ __forceinline__ short8 load8f_bf(const float* __restrict__ p) {
  const float4 a = *(const float4*)p;
  const float4 b = *(const float4*)(p + 4);
  short8 r;
  r[0]=f2bf(a.x); r[1]=f2bf(a.y); r[2]=f2bf(a.z); r[3]=f2bf(a.w);
  r[4]=f2bf(b.x); r[5]=f2bf(b.y); r[6]=f2bf(b.z); r[7]=f2bf(b.w);
  return r;
}

__device__ __forceinline__ short8 load8f_bf_sum(const float* __restrict__ p,
                                                const float* __restrict__ q) {
  const float4 a = *(const float4*)p, b = *(const float4*)(p + 4);
  const float4 c = *(const float4*)q, d = *(const float4*)(q + 4);
  short8 r;
  r[0]=f2bf(a.x+c.x); r[1]=f2bf(a.y+c.y); r[2]=f2bf(a.z+c.z); r[3]=f2bf(a.w+c.w);
  r[4]=f2bf(b.x+d.x); r[5]=f2bf(b.y+d.y); r[6]=f2bf(b.z+d.z); r[7]=f2bf(b.w+d.w);
  return r;
}

// 16B exchange load. FAST: sc0 (XCD-L2 coherent); result MUST pass a fence
// before use. SLOW: agent-scope atomics (compiler-tracked).
template<bool FAST>
__device__ __forceinline__ u32x4 xld16(const uint16_t* p) {
  if constexpr (FAST) {
    u32x4 r;
    asm volatile("global_load_dwordx4 %0, %1, off sc0"
                 : "=v"(r) : "v"((uint64_t)p));
    return r;
  } else {
    union { uint64_t u[2]; u32x4 v; } r;
    const uint64_t* q = (const uint64_t*)p;
    r.u[0] = __hip_atomic_load(q,     __ATOMIC_RELAXED, __HIP_MEMORY_SCOPE_AGENT);
    r.u[1] = __hip_atomic_load(q + 1, __ATOMIC_RELAXED, __HIP_MEMORY_SCOPE_AGENT);
    return r.v;
  }
}

template<bool FAST>
__device__ __forceinline__ void fence22(u32x4 (&a)[2][2]) {
  if constexpr (FAST)
    asm volatile("s_waitcnt vmcnt(0)"
                 : "+v"(a[0][0]), "+v"(a[0][1]), "+v"(a[1][0]), "+v"(a[1][1]));
}

template<bool FAST>
__device__ __forceinline__ uint32_t ldflag(const uint32_t* p) {
  if constexpr (FAST) {
    uint32_t r;
    asm volatile("global_load_dword %0, %1, off sc0\n\ts_waitcnt vmcnt(0)"
                 : "=v"(r) : "v"((uint64_t)p));
    return r;
  } else {
    return __hip_atomic_load(p, __ATOMIC_RELAXED, __HIP_MEMORY_SCOPE_AGENT);
  }
}

template<bool FAST>
__device__ __forceinline__ void st4(uint32_t* p, uint32_t v) {
  if constexpr (FAST)
    asm volatile("global_store_dword %0, %1, off sc0"
                 :: "v"((uint64_t)p), "v"(v) : "memory");
  else
    __hip_atomic_store(p, v, __ATOMIC_RELAXED, __HIP_MEMORY_SCOPE_AGENT);
}

template<bool FAST>
__device__ __forceinline__ void st2(uint16_t* p, uint16_t v) {
  if constexpr (FAST)
    asm volatile("global_store_short %0, %1, off sc0"
                 :: "v"((uint64_t)p), "v"((uint32_t)v) : "memory");
  else
    __hip_atomic_store(p, v, __ATOMIC_RELAXED, __HIP_MEMORY_SCOPE_AGENT);
}

__device__ __forceinline__ float sigm(float x)  { return 1.0f / (1.0f + __expf(-x)); }
__device__ __forceinline__ float tanh_(float x) { return 1.0f - 2.0f / (1.0f + __expf(2.0f * x)); }

#define BC8(v) __builtin_bit_cast(short8, v)

template<bool FAST>
__device__ __forceinline__ void body(
    const float* __restrict__ x,
    const float* __restrict__ Wih1, const float* __restrict__ Whh1,
    const float* __restrict__ bih1, const float* __restrict__ bhh1,
    const float* __restrict__ W1,   const float* __restrict__ b1,
    const float* __restrict__ Wih2, const float* __restrict__ Whh2,
    const float* __restrict__ bih2, const float* __restrict__ bhh2,
    float* __restrict__ out,
    uint32_t* __restrict__ bar,
    uint16_t* __restrict__ hbuf,
    uint16_t (&hsh)[32][16], float (&osh)[32][16],
    f32x4 (&red)[4][4][2][64])
{
  const int tid = threadIdx.x;
  const int l   = tid & 63;
  const int wv  = tid >> 6;
  const int blk = blockIdx.x;
  const int gid = (blk & 7) | ((blk >> 7) << 3);   // group: same blk%8 (XCD locality)
  const int mid = (blk >> 3) & 15;
  const int bg  = gid * 32;

  const int nl   = l & 15;
  const int kc   = l >> 4;
  const int gate = nl >> 2;
  const int cm   = nl & 3;
  const int grow = gate * H_ + mid * 16 + wv * 4 + cm;   // own-wave weight row
  const size_t wk = (size_t)wv * 64;                     // this wave's k-slice base

  const int POLL_MAX = FAST ? 50000 : 2000000;

  // flags: one 32B sector per wave-flag; 2 KiB per group
  uint32_t* flags = bar + (size_t)gid * 512;
  const int myflag = (mid * 4 + wv) * 8;

  uint16_t* slot0 = hbuf;
  uint16_t* slot1 = hbuf + (size_t)B_ * H_;
  uint16_t* slot2 = hbuf + (size_t)2 * B_ * H_;

  auto arrive = [&](int target) {
    asm volatile("s_waitcnt vmcnt(0)" ::: "memory");   // my stores are in L2/MALL
    if (l == 0) st4<FAST>(&flags[myflag], (uint32_t)target);
  };
  auto poll = [&](int target) {
    int g = 0;
    while ((int)ldflag<FAST>(&flags[l * 8]) < target) {
      __builtin_amdgcn_s_sleep(1);
      if (++g > POLL_MAX) break;  // fail-wrong, not hang
    }
    asm volatile("" ::: "memory");
  };
  auto ldsbar = [&]() {
    asm volatile("s_waitcnt lgkmcnt(0)\n\ts_barrier" ::: "memory");
  };

  // weight row base for n-tile nt (cols mid*16 + nt*4 + cm, gate-major rows)
  auto wrow = [&](int nt) { return (size_t)(gate * H_ + mid * 16 + nt * 4 + cm) * H_; };

  // ---- encoder weight k-slices: fw*_sl[nt][kt] = W[n-tile nt][k = wk+kt*32+kc*8..] ----
  short8 fwa_sl[4][2], fwb_sl[4][2];
#pragma unroll
  for (int nt = 0; nt < 4; ++nt)
#pragma unroll
    for (int kt = 0; kt < 2; ++kt) {
      const size_t o = wrow(nt) + wk + kt * 32 + kc * 8;
      fwa_sl[nt][kt] = load8f_bf(Wih1 + o);
      fwb_sl[nt][kt] = load8f_bf(Whh1 + o);
    }
  float bias = bih1[grow] + bhh1[grow];

  float cst[2][4];
#pragma unroll
  for (int mt = 0; mt < 2; ++mt)
#pragma unroll
    for (int r = 0; r < 4; ++r) cst[mt][r] = 0.0f;

  f32x4 accN[2][4];  // partial z (this wave's k-slice) for all 4 n-tiles

  // cross-wave K-reduction: partials -> full-K acc for own n-tile (nt == wv).
  // red writes/reads are lane-contiguous b128 -> conflict-free.
  auto reduce = [&](f32x4 (&acc)[2]) {
#pragma unroll
    for (int nt = 0; nt < 4; ++nt)
      if (nt != wv)
#pragma unroll
        for (int mt = 0; mt < 2; ++mt)
          red[nt][wv][mt][l] = accN[mt][nt];
    ldsbar();
#pragma unroll
    for (int mt = 0; mt < 2; ++mt) acc[mt] = accN[mt][wv];
#pragma unroll
    for (int ws = 0; ws < 4; ++ws)
      if (ws != wv)
#pragma unroll
        for (int mt = 0; mt < 2; ++mt) acc[mt] += red[wv][ws][mt][l];
  };

  // gate math + LDS gather-write (hn only for r==gate; each (mt,kc,gate,cm) unique)
  auto epi = [&](const f32x4* acc, float bias_, bool wout) {
    const int rb = (l & 48) | cm;
#pragma unroll
    for (int mt = 0; mt < 2; ++mt) {
      float hn = 0.f;
#pragma unroll
      for (int r = 0; r < 4; ++r) {
        float z = acc[mt][r] + bias_;
        float a = (gate == 2) ? tanh_(z) : sigm(z);
        float ti = __shfl(a, rb,      64);
        float tf = __shfl(a, rb | 4,  64);
        float tg = __shfl(a, rb | 8,  64);
        float to = __shfl(a, rb | 12, 64);
        float cn = tf * cst[mt][r] + ti * tg;
        cst[mt][r] = cn;
        if (r == gate) hn = to * tanh_(cn);
      }
      hsh[mt * 16 + kc * 4 + gate][wv * 4 + cm] = (uint16_t)f2bf(hn);
      if (wout) osh[mt * 16 + kc * 4 + gate][wv * 4 + cm] = hn;
    }
  };

  const int gb = tid >> 3;          // gather: b_loc 0..31
  const int gc = tid & 7;           // 4B chunk within the 32B row-chunk

  // x-part partial MFMAs for step t (k-slice only) -> runs post-flag, pre-poll
  auto xmfma = [&](int t) {
#pragma unroll
    for (int mt = 0; mt < 2; ++mt) {
      const float* xr = x + ((size_t)(bg + mt * 16 + nl) * T_ + t) * H_ + wk + kc * 8;
      short8 af0 = load8f_bf(xr);
      short8 af1 = load8f_bf(xr + 32);
#pragma unroll
      for (int nt = 0; nt < 4; ++nt) {
        f32x4 a = {0.f, 0.f, 0.f, 0.f};
        a = __builtin_amdgcn_mfma_f32_16x16x32_bf16(af0, fwa_sl[nt][0], a, 0, 0, 0);
        a = __builtin_amdgcn_mfma_f32_16x16x32_bf16(af1, fwa_sl[nt][1], a, 0, 0, 0);
        accN[mt][nt] = a;
      }
    }
  };
  xmfma(0);

  // ---------------- encoder ----------------
  for (int t = 0; t < T_; ++t) {
    if (t > 0) {
      poll(t);
      const uint16_t* hs = (t & 1) ? slot1 : slot0;
      u32x4 h4[2][2];
#pragma unroll
      for (int mt = 0; mt < 2; ++mt)
#pragma unroll
        for (int kt = 0; kt < 2; ++kt)
          h4[mt][kt] = xld16<FAST>(hs + (size_t)(bg + mt * 16 + nl) * H_ + wk + kt * 32 + kc * 8);
      fence22<FAST>(h4);
#pragma unroll
      for (int mt = 0; mt < 2; ++mt)
#pragma unroll
        for (int nt = 0; nt < 4; ++nt) {
          accN[mt][nt] = __builtin_amdgcn_mfma_f32_16x16x32_bf16(BC8(h4[mt][0]), fwb_sl[nt][0], accN[mt][nt], 0, 0, 0);
          accN[mt][nt] = __builtin_amdgcn_mfma_f32_16x16x32_bf16(BC8(h4[mt][1]), fwb_sl[nt][1], accN[mt][nt], 0, 0, 0);
        }
    }
    f32x4 acc[2];
    reduce(acc);
    epi(acc, bias, false);
    ldsbar();
    uint16_t* hw = ((t + 1) & 1) ? slot1 : slot0;
    {
      uint32_t hv = *(const uint32_t*)&hsh[gb][gc * 2];
      st4<FAST>((uint32_t*)&hw[(size_t)(bg + gb) * H_ + mid * 16 + gc * 2], hv);
    }
    arrive(t + 1);
    if (t + 1 < T_) xmfma(t + 1);   // overlapped with peers' arrival
  }

  // ---------------- x_end = h1 @ W1.T + b1  (h1 in slot0; K-split + reduce) ----------------
  poll(T_);
  {
    const int xcol = mid * 16 + nl;
    short8 fw1_sl[2];
    fw1_sl[0] = load8f_bf(W1 + (size_t)xcol * H_ + wk + kc * 8);
    fw1_sl[1] = load8f_bf(W1 + (size_t)xcol * H_ + wk + 32 + kc * 8);
    u32x4 h4[2][2];
#pragma unroll
    for (int mt = 0; mt < 2; ++mt)
#pragma unroll
      for (int kt = 0; kt < 2; ++kt)
        h4[mt][kt] = xld16<FAST>(slot0 + (size_t)(bg + mt * 16 + nl) * H_ + wk + kt * 32 + kc * 8);
    fence22<FAST>(h4);
#pragma unroll
    for (int mt = 0; mt < 2; ++mt) {
      f32x4 p_ = {0.f, 0.f, 0.f, 0.f};
      p_ = __builtin_amdgcn_mfma_f32_16x16x32_bf16(BC8(h4[mt][0]), fw1_sl[0], p_, 0, 0, 0);
      p_ = __builtin_amdgcn_mfma_f32_16x16x32_bf16(BC8(h4[mt][1]), fw1_sl[1], p_, 0, 0, 0);
      red[0][wv][mt][l] = p_;
    }
    ldsbar();
    if (wv == 0) {
      float bb = b1[xcol];
#pragma unroll
      for (int mt = 0; mt < 2; ++mt) {
        f32x4 s = red[0][0][mt][l];
        s += red[0][1][mt][l]; s += red[0][2][mt][l]; s += red[0][3][mt][l];
#pragma unroll
        for (int r = 0; r < 4; ++r)
          st2<FAST>(&slot2[(size_t)(bg + mt * 16 + kc * 4 + r) * H_ + xcol],
                    (uint16_t)f2bf(s[r] + bb));
      }
    }
  }
  arrive(T_ + 1);
  // NOTE: peers' next red-write happens only after poll(T_+1), which requires
  // wave0's flag, set after its red-reads -> no extra barrier needed.

  // decoder weight prep in the window
  short8 fwa2_sl[4][2], fwb2_sl[4][2], fws_sl[4][2];
#pragma unroll
  for (int nt = 0; nt < 4; ++nt)
#pragma unroll
    for (int kt = 0; kt < 2; ++kt) {
      const float* pa = Wih2 + wrow(nt) + wk + kt * 32 + kc * 8;
      const float* pb = Whh2 + wrow(nt) + wk + kt * 32 + kc * 8;
      fwa2_sl[nt][kt] = load8f_bf(pa);
      fwb2_sl[nt][kt] = load8f_bf(pb);
      fws_sl[nt][kt]  = load8f_bf_sum(pa, pb);   // bf16(Wih2+Whh2), summed in fp32
    }
  bias = bih2[grow] + bhh2[grow];
  poll(T_ + 1);

  // ---------------- decoder t=0 (x_end w/ fwa2, h1 w/ fwb2) ----------------
  {
    u32x4 a4[2][2], b4[2][2];
#pragma unroll
    for (int mt = 0; mt < 2; ++mt)
#pragma unroll
      for (int kt = 0; kt < 2; ++kt) {
        const size_t ro = (size_t)(bg + mt * 16 + nl) * H_ + wk + kt * 32 + kc * 8;
        a4[mt][kt] = xld16<FAST>(slot2 + ro);
        b4[mt][kt] = xld16<FAST>(slot0 + ro);
      }
    fence22<FAST>(a4);
    fence22<FAST>(b4);
#pragma unroll
    for (int mt = 0; mt < 2; ++mt)
#pragma unroll
      for (int nt = 0; nt < 4; ++nt) {
        f32x4 a = {0.f, 0.f, 0.f, 0.f};
        a = __builtin_amdgcn_mfma_f32_16x16x32_bf16(BC8(a4[mt][0]), fwa2_sl[nt][0], a, 0, 0, 0);
        a = __builtin_amdgcn_mfma_f32_16x16x32_bf16(BC8(a4[mt][1]), fwa2_sl[nt][1], a, 0, 0, 0);
        a = __builtin_amdgcn_mfma_f32_16x16x32_bf16(BC8(b4[mt][0]), fwb2_sl[nt][0], a, 0, 0, 0);
        a = __builtin_amdgcn_mfma_f32_16x16x32_bf16(BC8(b4[mt][1]), fwb2_sl[nt][1], a, 0, 0, 0);
        accN[mt][nt] = a;
      }
    f32x4 acc[2];
    reduce(acc);
    epi(acc, bias, true);
    ldsbar();
    uint32_t hv = *(const uint32_t*)&hsh[gb][gc * 2];
    uint64_t ov = *(const uint64_t*)&osh[gb][gc * 2];
    st4<FAST>((uint32_t*)&slot1[(size_t)(bg + gb) * H_ + mid * 16 + gc * 2], hv);
    arrive(T_ + 2);
    *(uint64_t*)&out[((size_t)(bg + gb) * T_ + (T_ - 2)) * H_ + mid * 16 + gc * 2] = ov;
  }

  // ---------------- decoder t>=1 (merged weights; x_t == h_{t-1}) ----------------
  for (int t = 1; t < T_; ++t) {
    poll(T_ + 1 + t);
    const uint16_t* hs = (t & 1) ? slot1 : slot0;
    u32x4 h4[2][2];
#pragma unroll
    for (int mt = 0; mt < 2; ++mt)
#pragma unroll
      for (int kt = 0; kt < 2; ++kt)
        h4[mt][kt] = xld16<FAST>(hs + (size_t)(bg + mt * 16 + nl) * H_ + wk + kt * 32 + kc * 8);
    fence22<FAST>(h4);
#pragma unroll
    for (int mt = 0; mt < 2; ++mt)
#pragma unroll
      for (int nt = 0; nt < 4; ++nt) {
        f32x4 a = {0.f, 0.f, 0.f, 0.f};
        a = __builtin_amdgcn_mfma_f32_16x16x32_bf16(BC8(h4[mt][0]), fws_sl[nt][0], a, 0, 0, 0);
        a = __builtin_amdgcn_mfma_f32_16x16x32_bf16(BC8(h4[mt][1]), fws_sl[nt][1], a, 0, 0, 0);
        accN[mt][nt] = a;
      }
    f32x4 acc[2];
    reduce(acc);
    epi(acc, bias, true);
    ldsbar();
    const int j = (t == T_ - 1) ? (T_ - 1) : (T_ - 2 - t);
    uint32_t hv = *(const uint32_t*)&hsh[gb][gc * 2];
    uint64_t ov = *(const uint64_t*)&osh[gb][gc * 2];
    if (t + 1 < T_) {
      uint16_t* hw = ((t + 1) & 1) ? slot1 : slot0;
      st4<FAST>((uint32_t*)&hw[(size_t)(bg + gb) * H_ + mid * 16 + gc * 2], hv);
      arrive(T_ + 2 + t);
    }
    *(uint64_t*)&out[((size_t)(bg + gb) * T_ + j) * H_ + mid * 16 + gc * 2] = ov;
  }
}

__global__ __launch_bounds__(256, 1) void encdec_kernel(
    const float* __restrict__ x,
    const float* __restrict__ Wih1, const float* __restrict__ Whh1,
    const float* __restrict__ bih1, const float* __restrict__ bhh1,
    const float* __restrict__ W1,   const float* __restrict__ b1,
    const float* __restrict__ Wih2, const float* __restrict__ Whh2,
    const float* __restrict__ bih2, const float* __restrict__ bhh2,
    float* __restrict__ out,
    uint32_t* __restrict__ bar,
    uint16_t* __restrict__ hbuf)
{
  __shared__ f32x4   red[4][4][2][64];  // 32KB cross-wave K-reduction
  __shared__ uint16_t hsh[32][16];      // block's h tile (b_loc x col16), bf16
  __shared__ float    osh[32][16];      // block's out tile, fp32 (decoder)

  const int tid = threadIdx.x;
  const int l   = tid & 63;
  const int blk = blockIdx.x;
  const int gid = (blk & 7) | ((blk >> 7) << 3);
  const int mid = (blk >> 3) & 15;

  uint32_t* xw = bar + (size_t)gid * 512;  // words mod 8 in {1,2,3}: not used by body

  // --- phase 1: XCC-ID consensus (agent scope; reliable) ---
  // s_getreg hwreg(HW_REG_XCC_ID=20, offset=0, size=4) -> imm 20|(3<<11)
  const uint32_t my_xcc = (uint32_t)__builtin_amdgcn_s_getreg(6164) & 0xffu;
  if (tid == 0)
    __hip_atomic_store(&xw[mid * 8 + 1], 0x100u | my_xcc,
                       __ATOMIC_RELAXED, __HIP_MEMORY_SCOPE_AGENT);
  uint32_t pv = 0; int g = 0; bool seen = true;
  for (;;) {
    pv = __hip_atomic_load(&xw[(l & 15) * 8 + 1],
                           __ATOMIC_RELAXED, __HIP_MEMORY_SCOPE_AGENT);
    if (pv & 0x100u) break;
    __builtin_amdgcn_s_sleep(1);
    if (++g > 1000000) { seen = false; break; }
  }
  const bool same_xcd = __all((int)(seen && ((pv & 0xffu) == my_xcc)));

  // --- phase 2: sc0 visibility self-test (bounded; only if same XCD) ---
  int verdict = 0;
  if (same_xcd) {
    if (tid == 0) st4<true>(&xw[mid * 8 + 2], 0xA5A5u);
    g = 0; bool s2 = true;
    for (;;) {
      uint32_t qv = ldflag<true>(&xw[(l & 15) * 8 + 2]);
      if (qv == 0xA5A5u) break;
      __builtin_amdgcn_s_sleep(1);
      if (++g > 20000) { s2 = false; break; }   // ~ms bound; normal: <100 iters
    }
    verdict = __all((int)s2) ? 1 : 0;
  }

  // --- phase 3: unanimous-verdict exchange (agent scope; reliable) ---
  if (tid == 0)
    __hip_atomic_store(&xw[mid * 8 + 3], 0x200u | (uint32_t)verdict,
                       __ATOMIC_RELAXED, __HIP_MEMORY_SCOPE_AGENT);
  uint32_t vv = 0; g = 0; seen = true;
  for (;;) {
    vv = __hip_atomic_load(&xw[(l & 15) * 8 + 3],
                           __ATOMIC_RELAXED, __HIP_MEMORY_SCOPE_AGENT);
    if (vv & 0x200u) break;
    __builtin_amdgcn_s_sleep(1);
    if (++g > 1000000) { seen = false; break; }
  }
  const bool fast = __all((int)(seen && (vv & 1u)));

  if (fast)
    body<true>(x, Wih1, Whh1, bih1, bhh1, W1, b1, Wih2, Whh2, bih2, bhh2,
               out, bar, hbuf, hsh, osh, red);
  else
    body<false>(x, Wih1, Whh1, bih1, bhh1, W1, b1, Wih2, Whh2, bih2, bhh2,
                out, bar, hbuf, hsh, osh, red);
}

extern "C" void kernel_launch(void* const* d_in, const int* in_sizes, int n_in,
                              void* d_out, int out_size, void* d_ws, size_t ws_size,
                              hipStream_t stream) {
  const float* x    = (const float*)d_in[0];
  const float* Wih1 = (const float*)d_in[1];
  const float* Whh1 = (const float*)d_in[2];
  const float* bih1 = (const float*)d_in[3];
  const float* bhh1 = (const float*)d_in[4];
  const float* W1   = (const float*)d_in[5];
  const float* b1   = (const float*)d_in[6];
  const float* Wih2 = (const float*)d_in[7];
  const float* Whh2 = (const float*)d_in[8];
  const float* bih2 = (const float*)d_in[9];
  const float* bhh2 = (const float*)d_in[10];
  float* out = (float*)d_out;

  uint32_t* bar  = (uint32_t*)d_ws;                   // 16 groups x 2 KiB flag/consensus regions
  uint16_t* hbuf = (uint16_t*)((char*)d_ws + 32768);  // 3 bf16 (B,H) slots

  hipLaunchKernelGGL(encdec_kernel, dim3(256), dim3(256), 0, stream,
                     x, Wih1, Whh1, bih1, bhh1, W1, b1, Wih2, Whh2, bih2, bhh2,
                     out, bar, hbuf);
}